// Round 6
// baseline (32203.183 us; speedup 1.0000x reference)
//
#include <hip/hip_runtime.h>
#include <hip/hip_bf16.h>

typedef __attribute__((ext_vector_type(8))) short bh8;     // 8 bf16 (4 VGPRs)
typedef __attribute__((ext_vector_type(4))) float fx4;     // MFMA C/D
typedef __attribute__((ext_vector_type(4))) unsigned int ux4;
typedef unsigned int u32;
typedef unsigned long long u64;

#define S_LEN 2048
#define OUTBASE 16777216   // 8*2048*1024

__device__ __forceinline__ unsigned short f2bf(float f) {
  __hip_bfloat16 h = __float2bfloat16(f);
  unsigned short u; __builtin_memcpy(&u, &h, 2); return u;
}
__device__ __forceinline__ float bf2f(unsigned short u) {
  __hip_bfloat16 h; __builtin_memcpy(&h, &u, 2); return __bfloat162float(h);
}

// ---------------- prep: transpose + bf16-convert weights ----------------
__global__ __launch_bounds__(256) void prep_w(
    const float* __restrict__ Wi, const float* __restrict__ Wf,
    const float* __restrict__ Wg, const float* __restrict__ Wo,
    const float* __restrict__ Weg,
    __hip_bfloat16* __restrict__ WxT, __hip_bfloat16* __restrict__ WhT,
    __hip_bfloat16* __restrict__ WegT) {
  __shared__ float tile[32][33];
  const int z = blockIdx.z;
  const float* src = (z==0)?Wi:(z==1)?Wf:(z==2)?Wg:(z==3)?Wo:Weg;
  const int kbase = blockIdx.y * 32, cbase = blockIdx.x * 32;
  if (z == 4 && kbase >= 1024) return;
  const int tx = threadIdx.x, ty = threadIdx.y;
#pragma unroll
  for (int rr = 0; rr < 4; ++rr)
    tile[ty*4+rr][tx] = src[(size_t)(kbase + ty*4+rr)*1024 + cbase + tx];
  __syncthreads();
#pragma unroll
  for (int rr = 0; rr < 4; ++rr) {
    int c = cbase + ty*4+rr;
    int k = kbase + tx;
    __hip_bfloat16 v = __float2bfloat16(tile[tx][ty*4+rr]);
    if (z < 4) {
      if (k < 1024) WxT[(size_t)(z*1024 + c)*1024 + k] = v;
      else          WhT[(size_t)(z*1024 + c)*1024 + (k-1024)] = v;
    } else {
      WegT[(size_t)c*1024 + k] = v;
    }
  }
}

// ---------------- init: zero tagged h/g exchange buffers; build bias concat ----
__global__ __launch_bounds__(256) void init_k(
    u32* h_tag, u32* g_tag,
    const float* __restrict__ bi, const float* __restrict__ bfv,
    const float* __restrict__ bg, const float* __restrict__ bo,
    float* __restrict__ bcat) {
  int t = blockIdx.x * 256 + threadIdx.x;
  if (t < 8192) { h_tag[t] = 0u; g_tag[t] = 0u; }   // value bf16(0), tag 0
  if (t < 4096) {
    float v = (t < 1024) ? bi[t] : (t < 2048) ? bfv[t-1024]
            : (t < 3072) ? bg[t-2048] : bo[t-3072];
    bcat[t] = v;
  }
}

// ---------------- convert x to bf16 ----------------
__global__ __launch_bounds__(256) void conv_x(const float* __restrict__ x,
                                              __hip_bfloat16* __restrict__ xbf) {
  size_t i = ((size_t)blockIdx.x * 256 + threadIdx.x) * 8;
  fx4 a = *reinterpret_cast<const fx4*>(x + i);
  fx4 b = *reinterpret_cast<const fx4*>(x + i + 4);
  unsigned short o[8];
#pragma unroll
  for (int u = 0; u < 4; ++u) { o[u] = f2bf(a[u]); o[4+u] = f2bf(b[u]); }
  bh8 v; __builtin_memcpy(&v, o, 16);
  *reinterpret_cast<bh8*>(xbf + i) = v;
}

// ---------------- phase-1 GEMM: XG[s*8+b][c] = x @ Wx + bias (bf16) ----------------
__global__ __launch_bounds__(256) void gemm_x(
    const __hip_bfloat16* __restrict__ xbf,
    const __hip_bfloat16* __restrict__ WxT,
    const float* __restrict__ bcat,
    __hip_bfloat16* __restrict__ XG) {
  __shared__ bh8 ldsv[2048];                 // 32 KB
  char* lds = reinterpret_cast<char*>(ldsv);
  const int tid = threadIdx.x;
  const int bn = blockIdx.x, bm = blockIdx.y;
  const int lane = tid & 63, wid = tid >> 6;
  const int wr = wid >> 1, wc = wid & 1;
  fx4 acc[4][4] = {};
  for (int kb = 0; kb < 16; ++kb) {
    __syncthreads();
#pragma unroll
    for (int c = 0; c < 4; ++c) {
      int cid = tid + 256 * c;
      int r = cid >> 3, kc = cid & 7;
      bh8 va = *reinterpret_cast<const bh8*>(xbf + (size_t)(bm*128 + r)*1024 + kb*64 + kc*8);
      int off = (r*128 + kc*16) ^ ((r & 7) << 4);
      *reinterpret_cast<bh8*>(lds + off) = va;
      bh8 vb = *reinterpret_cast<const bh8*>(WxT + (size_t)(bn*128 + r)*1024 + kb*64 + kc*8);
      *reinterpret_cast<bh8*>(lds + 16384 + off) = vb;
    }
    __syncthreads();
#pragma unroll
    for (int ks = 0; ks < 2; ++ks) {
      bh8 af[4], bfr[4];
      int ac = ks*64 + (lane >> 4) * 16;
#pragma unroll
      for (int i = 0; i < 4; ++i) {
        int ar = wr*64 + i*16 + (lane & 15);
        af[i] = *reinterpret_cast<const bh8*>(lds + ((ar*128 + ac) ^ ((ar & 7) << 4)));
        int br = wc*64 + i*16 + (lane & 15);
        bfr[i] = *reinterpret_cast<const bh8*>(lds + 16384 + ((br*128 + ac) ^ ((br & 7) << 4)));
      }
#pragma unroll
      for (int i = 0; i < 4; ++i)
#pragma unroll
        for (int jn = 0; jn < 4; ++jn)
          acc[i][jn] = __builtin_amdgcn_mfma_f32_16x16x32_bf16(af[i], bfr[jn], acc[i][jn], 0, 0, 0);
    }
  }
#pragma unroll
  for (int i = 0; i < 4; ++i) {
    int rbase = bm*128 + wr*64 + i*16 + (lane >> 4) * 4;
#pragma unroll
    for (int jn = 0; jn < 4; ++jn) {
      int col = bn*128 + wc*64 + jn*16 + (lane & 15);
      float bias = bcat[col];
#pragma unroll
      for (int jj = 0; jj < 4; ++jj) {
        int r = rbase + jj;
        int b = r >> 11, s = r & 2047;
        XG[(size_t)(s*8 + b)*4096 + col] = __float2bfloat16(acc[i][jn][jj] + bias);
      }
    }
  }
}

// ---------------- persistent recurrence kernel (tagged-data exchange) ----------------
struct __align__(16) RecurLds {
  short wa[16 * 1024];        // 32KB gate-weight slice, col-major, xor-swizzled
  short weg[4 * 1024];        // 8KB Weg slice
  float exk[2][4][8][16];     // double-buffered K-split partial D (A=0, B=1)
  unsigned short xg[2][8][16];// XG slice double-buffer
};

// Incremental batched tagged poll. pend is wave-uniform (built from __all
// votes): each round issues loads ONLY for pending chunks (back-to-back ->
// ~1 L3 RTT), validates them, clears bits. First round reads all 32 u64;
// later rounds touch only stragglers. The final registers ARE the MFMA
// A-operand data (detection == delivery; no fences, no separate flags).
__device__ __forceinline__ void pollread(const u64* base, u32 etag,
                                         u32 (&a0)[8][4]) {
  u64 q[8][4];
  int pend = 0xFF;
  do {
#pragma unroll
    for (int ks = 0; ks < 8; ++ks) {
      if (pend & (1 << ks)) {
#pragma unroll
        for (int u = 0; u < 4; ++u)
          q[ks][u] = __hip_atomic_load(const_cast<u64*>(base + ks*16 + u),
                                       __ATOMIC_RELAXED, __HIP_MEMORY_SCOPE_AGENT);
      }
    }
    int newpend = 0;
#pragma unroll
    for (int ks = 0; ks < 8; ++ks) {
      if (pend & (1 << ks)) {
        u32 bad = 0;
#pragma unroll
        for (int u = 0; u < 4; ++u) {
          u32 lo = (u32)q[ks][u], hi = (u32)(q[ks][u] >> 32);
          bad |= ((lo ^ etag) | (hi ^ etag)) & 0xFFFFu;
        }
        if (!__all(bad == 0)) newpend |= (1 << ks);
      }
    }
    pend = newpend;
  } while (pend);
#pragma unroll
  for (int ks = 0; ks < 8; ++ks)
#pragma unroll
    for (int u = 0; u < 4; ++u) {
      u32 lo = (u32)q[ks][u], hi = (u32)(q[ks][u] >> 32);
      a0[ks][u] = (lo >> 16) | (hi & 0xFFFF0000u);
    }
}

__global__ __launch_bounds__(256, 1) void recur(
    const __hip_bfloat16* __restrict__ WhT,
    const __hip_bfloat16* __restrict__ WegT,
    const __hip_bfloat16* __restrict__ XG,
    const float* __restrict__ beg,
    u32* h_tag, u32* g_tag, float* d_out) {
  __shared__ RecurLds L;
  const int j = blockIdx.x;            // 0..255, owns h-cols [4j,4j+4)
  const int tid = threadIdx.x;
  const int w = tid >> 6, lane = tid & 63;
  const int col16 = lane & 15, rgrp = lane >> 4;

  // load weight slices into LDS (col-major, xor-swizzled per 16B chunk)
  for (int cid = tid; cid < 2048; cid += 256) {
    int cc = cid >> 7, kc = cid & 127;
    int gate = cc >> 2, c = cc & 3;
    bh8 v = *reinterpret_cast<const bh8*>(&WhT[((size_t)(gate*1024 + j*4 + c))*1024 + kc*8]);
    *reinterpret_cast<bh8*>(reinterpret_cast<char*>(L.wa) + ((cc*2048 + kc*16) ^ ((cc & 7) << 4))) = v;
  }
  for (int cid = tid; cid < 512; cid += 256) {
    int cc = cid >> 7, kc = cid & 127;
    bh8 v = *reinterpret_cast<const bh8*>(&WegT[((size_t)(j*4 + cc))*1024 + kc*8]);
    *reinterpret_cast<bh8*>(reinterpret_cast<char*>(L.weg) + ((cc*2048 + kc*16) ^ (cc << 4))) = v;
  }
  float begv = 0.f, c_st = 0.f, n_st = 0.f;
  const int b32 = tid >> 2, c32 = tid & 3;   // roles for tid<32
  if (tid < 32) begv = beg[j*4 + c32];
  if (tid < 32) {  // stage XG[0]
    u64 v = *reinterpret_cast<const u64*>(&XG[((size_t)b32)*4096 + c32*1024 + j*4]);
    *reinterpret_cast<u64*>(&L.xg[0][b32][c32*4]) = v;
  }
  __syncthreads();

  // All 64 lanes poll: lanes col16>=8 mirror col16-8 (same cachelines, no
  // extra L2+ traffic). Their garbage A-fragments only affect D rows 8..15,
  // which are never read.
  const u64* hbase = reinterpret_cast<const u64*>(h_tag) + ((col16 & 7)*512 + w*128 + rgrp*4);
  const u64* gbase = reinterpret_cast<const u64*>(g_tag) + ((col16 & 7)*512 + w*128 + rgrp*4);

#pragma unroll 1
  for (int t = 0; t < S_LEN; ++t) {
    // prefetch next step's XG slice on wave 1 (off wave 0's critical path)
    if (w == 1 && lane < 32 && t < S_LEN - 1) {
      int bb = lane >> 2, cg = lane & 3;
      u64 v = *reinterpret_cast<const u64*>(
          &XG[((size_t)(t+1)*8 + bb)*4096 + cg*1024 + j*4]);
      *reinterpret_cast<u64*>(&L.xg[(t+1) & 1][bb][cg*4]) = v;
    }
    // ---- phase A: preacts = h @ Wh (K split over 4 waves) ----
    u32 a0[8][4];
    pollread(hbase, (u32)t, a0);
    fx4 d = {0.f, 0.f, 0.f, 0.f};
#pragma unroll
    for (int ks = 0; ks < 8; ++ks) {
      int koff = w*256 + ks*32 + rgrp*8;
      bh8 bfr = *reinterpret_cast<const bh8*>(
          reinterpret_cast<char*>(L.wa) + ((col16*2048 + koff*2) ^ ((col16 & 7) << 4)));
      ux4 uv = { a0[ks][0], a0[ks][1], a0[ks][2], a0[ks][3] };
      bh8 afr = __builtin_bit_cast(bh8, uv);
      d = __builtin_amdgcn_mfma_f32_16x16x32_bf16(afr, bfr, d, 0, 0, 0);
    }
    if (rgrp < 2) {
#pragma unroll
      for (int jj = 0; jj < 4; ++jj) L.exk[0][w][rgrp*4 + jj][col16] = d[jj];
    }
    __syncthreads();                       // exk[0] ready
    float i_v = 0.f, f_v = 0.f, o_v = 0.f, c_new = 0.f;
    if (tid < 32) {   // g first -> publish ASAP; then i/f/o/c off the wire
      float sg = L.exk[0][0][b32][8 + c32]  + L.exk[0][1][b32][8 + c32]
               + L.exk[0][2][b32][8 + c32]  + L.exk[0][3][b32][8 + c32]
               + bf2f(L.xg[t & 1][b32][8 + c32]);
      float g_v = tanhf(sg);
      u32 tg = ((u32)f2bf(g_v) << 16) | (u32)(t + 1);
      __hip_atomic_store(&g_tag[b32*1024 + j*4 + c32], tg,
                         __ATOMIC_RELAXED, __HIP_MEMORY_SCOPE_AGENT);
      float si = L.exk[0][0][b32][c32]      + L.exk[0][1][b32][c32]
               + L.exk[0][2][b32][c32]      + L.exk[0][3][b32][c32]
               + bf2f(L.xg[t & 1][b32][c32]);
      float sf = L.exk[0][0][b32][4 + c32]  + L.exk[0][1][b32][4 + c32]
               + L.exk[0][2][b32][4 + c32]  + L.exk[0][3][b32][4 + c32]
               + bf2f(L.xg[t & 1][b32][4 + c32]);
      float so = L.exk[0][0][b32][12 + c32] + L.exk[0][1][b32][12 + c32]
               + L.exk[0][2][b32][12 + c32] + L.exk[0][3][b32][12 + c32]
               + bf2f(L.xg[t & 1][b32][12 + c32]);
      i_v = 1.f / (1.f + expf(-si));
      f_v = 1.f / (1.f + expf(-sf));
      o_v = 1.f / (1.f + expf(-so));
      c_new = f_v * c_st + i_v * g_v; c_st = c_new;
    }
    // ---- phase B: e = g @ Weg (cols 4j..4j+4), n/h update ----
    u32 b0[8][4];
    pollread(gbase, (u32)(t + 1), b0);
    fx4 d2 = {0.f, 0.f, 0.f, 0.f};
#pragma unroll
    for (int ks = 0; ks < 8; ++ks) {
      int koff = w*256 + ks*32 + rgrp*8;
      bh8 bfr;
      if (col16 < 4)
        bfr = *reinterpret_cast<const bh8*>(
            reinterpret_cast<char*>(L.weg) + ((col16*2048 + koff*2) ^ (col16 << 4)));
      else
        bfr = bh8{0, 0, 0, 0, 0, 0, 0, 0};
      ux4 uv = { b0[ks][0], b0[ks][1], b0[ks][2], b0[ks][3] };
      bh8 afr = __builtin_bit_cast(bh8, uv);
      d2 = __builtin_amdgcn_mfma_f32_16x16x32_bf16(afr, bfr, d2, 0, 0, 0);
    }
    if (rgrp < 2 && col16 < 4) {
#pragma unroll
      for (int jj = 0; jj < 4; ++jj) L.exk[1][w][rgrp*4 + jj][col16] = d2[jj];
    }
    __syncthreads();                       // exk[1] ready
    if (tid < 32) {
      float s = L.exk[1][0][b32][c32] + L.exk[1][1][b32][c32]
              + L.exk[1][2][b32][c32] + L.exk[1][3][b32][c32] + begv;
      float e = expf(s);
      float n_new = f_v * n_st + i_v * e; n_st = n_new;
      float h_new = o_v * (c_new / n_new);
      if (t < S_LEN - 1) {
        u32 th = ((u32)f2bf(h_new) << 16) | (u32)(t + 1);
        __hip_atomic_store(&h_tag[b32*1024 + j*4 + c32], th,
                           __ATOMIC_RELAXED, __HIP_MEMORY_SCOPE_AGENT);
      }
      d_out[((size_t)b32*2048 + t)*1024 + j*4 + c32] = h_new;   // h history (pre-LN)
      if (t == S_LEN - 1) {
        d_out[OUTBASE +         (size_t)b32*1024 + j*4 + c32] = h_new;  // h_f
        d_out[OUTBASE +  8192 + (size_t)b32*1024 + j*4 + c32] = c_new;  // c_f
        d_out[OUTBASE + 16384 + (size_t)b32*1024 + j*4 + c32] = n_new;  // n_f
      }
    }
  }
}

// ---------------- residual + LayerNorm (in-place on d_out) ----------------
__global__ __launch_bounds__(256) void ln_k(const float* __restrict__ x,
                                            const float* __restrict__ gamma,
                                            const float* __restrict__ beta,
                                            float* __restrict__ out) {
  const int r = blockIdx.x, tid = threadIdx.x;
  float* orow = out + (size_t)r * 1024;
  const float* xrow = x + (size_t)r * 1024;
  fx4 h4 = *reinterpret_cast<const fx4*>(orow + tid*4);
  fx4 x4 = *reinterpret_cast<const fx4*>(xrow + tid*4);
  fx4 y = h4 + x4;
  float s = y[0] + y[1] + y[2] + y[3];
  float s2 = y[0]*y[0] + y[1]*y[1] + y[2]*y[2] + y[3]*y[3];
#pragma unroll
  for (int m = 1; m < 64; m <<= 1) { s += __shfl_xor(s, m, 64); s2 += __shfl_xor(s2, m, 64); }
  __shared__ float ps[4], ps2[4], stats[2];
  if ((tid & 63) == 0) { ps[tid >> 6] = s; ps2[tid >> 6] = s2; }
  __syncthreads();
  if (tid == 0) {
    float t1 = ps[0] + ps[1] + ps[2] + ps[3];
    float t2 = ps2[0] + ps2[1] + ps2[2] + ps2[3];
    float mu = t1 * (1.f / 1024.f);
    float var = t2 * (1.f / 1024.f) - mu * mu;
    stats[0] = mu; stats[1] = rsqrtf(var + 1e-5f);
  }
  __syncthreads();
  float mu = stats[0], rs = stats[1];
  fx4 g4 = *reinterpret_cast<const fx4*>(gamma + tid*4);
  fx4 b4 = *reinterpret_cast<const fx4*>(beta + tid*4);
  fx4 o4;
#pragma unroll
  for (int u = 0; u < 4; ++u) o4[u] = (y[u] - mu) * rs * g4[u] + b4[u];
  *reinterpret_cast<fx4*>(orow + tid*4) = o4;
}

extern "C" void kernel_launch(void* const* d_in, const int* in_sizes, int n_in,
                              void* d_out, int out_size, void* d_ws, size_t ws_size,
                              hipStream_t stream) {
  const float* x    = (const float*)d_in[0];
  const float* Wi   = (const float*)d_in[1];
  const float* bi   = (const float*)d_in[2];
  const float* Wf   = (const float*)d_in[3];
  const float* bfv  = (const float*)d_in[4];
  const float* Wg   = (const float*)d_in[5];
  const float* bg   = (const float*)d_in[6];
  const float* Wo   = (const float*)d_in[7];
  const float* bo   = (const float*)d_in[8];
  const float* Weg  = (const float*)d_in[9];
  const float* beg  = (const float*)d_in[10];
  const float* gamma= (const float*)d_in[11];
  const float* beta = (const float*)d_in[12];
  float* out = (float*)d_out;
  char* ws = (char*)d_ws;

  __hip_bfloat16* XG   = (__hip_bfloat16*)(ws);                    // 134217728 B
  __hip_bfloat16* xbf  = (__hip_bfloat16*)(ws + 134217728ull);     //  33554432 B
  __hip_bfloat16* WxT  = (__hip_bfloat16*)(ws + 167772160ull);     //   8388608 B
  __hip_bfloat16* WhT  = (__hip_bfloat16*)(ws + 176160768ull);     //   8388608 B
  __hip_bfloat16* WegT = (__hip_bfloat16*)(ws + 184549376ull);     //   2097152 B
  float* bcat          = (float*)(ws + 186646528ull);              //     16384 B
  u32* h_tag           = (u32*)(ws + 186662912ull);                //     32768 B
  u32* g_tag           = (u32*)(ws + 186695680ull);                //     32768 B

  prep_w<<<dim3(32, 64, 5), dim3(32, 8), 0, stream>>>(Wi, Wf, Wg, Wo, Weg, WxT, WhT, WegT);
  init_k<<<dim3(64), dim3(256), 0, stream>>>(h_tag, g_tag, bi, bfv, bg, bo, bcat);
  conv_x<<<dim3(8192), dim3(256), 0, stream>>>(x, xbf);
  gemm_x<<<dim3(32, 128), dim3(256), 0, stream>>>(xbf, WxT, bcat, XG);
  recur<<<dim3(256), dim3(256), 0, stream>>>(WhT, WegT, XG, beg, h_tag, g_tag, out);
  ln_k<<<dim3(16384), dim3(256), 0, stream>>>(x, gamma, beta, out);
}

// Round 7
// 8685.442 us; speedup vs baseline: 3.7077x; 3.7077x over previous
//
#include <hip/hip_runtime.h>
#include <hip/hip_bf16.h>

typedef __attribute__((ext_vector_type(8))) short bh8;     // 8 bf16 (4 VGPRs)
typedef __attribute__((ext_vector_type(4))) float fx4;     // MFMA C/D
typedef __attribute__((ext_vector_type(4))) unsigned int ux4;
typedef unsigned int u32;
typedef unsigned long long u64;

#define S_LEN 2048
#define OUTBASE 16777216   // 8*2048*1024

__device__ __forceinline__ unsigned short f2bf(float f) {
  __hip_bfloat16 h = __float2bfloat16(f);
  unsigned short u; __builtin_memcpy(&u, &h, 2); return u;
}
__device__ __forceinline__ float bf2f(unsigned short u) {
  __hip_bfloat16 h; __builtin_memcpy(&h, &u, 2); return __bfloat162float(h);
}

// ---------------- prep: transpose + bf16-convert Wx for the big GEMM ----------------
__global__ __launch_bounds__(256) void prep_w(
    const float* __restrict__ Wi, const float* __restrict__ Wf,
    const float* __restrict__ Wg, const float* __restrict__ Wo,
    __hip_bfloat16* __restrict__ WxT) {
  __shared__ float tile[32][33];
  const int z = blockIdx.z;
  const float* src = (z==0)?Wi:(z==1)?Wf:(z==2)?Wg:Wo;
  const int kbase = blockIdx.y * 32, cbase = blockIdx.x * 32;
  const int tx = threadIdx.x, ty = threadIdx.y;
#pragma unroll
  for (int rr = 0; rr < 4; ++rr)
    tile[ty*4+rr][tx] = src[(size_t)(kbase + ty*4+rr)*1024 + cbase + tx];
  __syncthreads();
#pragma unroll
  for (int rr = 0; rr < 4; ++rr) {
    int c = cbase + ty*4+rr;
    int k = kbase + tx;
    WxT[(size_t)(z*1024 + c)*1024 + k] = __float2bfloat16(tile[tx][ty*4+rr]);
  }
}

// ---------------- prep: gate-weight MFMA B-fragments (Wh part, rows 1024..2047) ----
// gfrag[((jb*4+g)*64 + ks*2 + ct)*64 + lane] = 8 bf16 of
//   W_g[1024 + ks*32 + (lane>>4)*8 + i][jb*32 + ct*16 + (lane&15)]
__global__ __launch_bounds__(128) void prep_gfrag(
    const float* __restrict__ Wi, const float* __restrict__ Wf,
    const float* __restrict__ Wg, const float* __restrict__ Wo,
    bh8* __restrict__ gfrag) {
  const int bx = blockIdx.x;                 // 4096 = 32 jb * 4 g * 32 ks
  const int jb = bx >> 7, g = (bx >> 5) & 3, ks = bx & 31;
  const int tid = threadIdx.x, lane = tid & 63, ct = tid >> 6;
  const float* W = (g==0)?Wi:(g==1)?Wf:(g==2)?Wg:Wo;
  const int col = jb*32 + ct*16 + (lane & 15);
  const int kb = ks*32 + ((lane >> 4) & 3)*8;
  unsigned short o[8];
#pragma unroll
  for (int i = 0; i < 8; ++i)
    o[i] = f2bf(W[(size_t)(1024 + kb + i)*1024 + col]);
  bh8 v; __builtin_memcpy(&v, o, 16);
  gfrag[((size_t)(jb*4 + g)*64 + ks*2 + ct)*64 + lane] = v;
}

// ---------------- prep: Weg MFMA B-fragments ----------------
__global__ __launch_bounds__(128) void prep_wegfrag(
    const float* __restrict__ Weg, bh8* __restrict__ wegfrag) {
  const int bx = blockIdx.x;                 // 1024 = 32 jb * 4 wv * 8 ks
  const int jb = bx >> 5, wv = (bx >> 3) & 3, ks = bx & 7;
  const int tid = threadIdx.x, lane = tid & 63, ct = tid >> 6;
  const int col = jb*32 + ct*16 + (lane & 15);
  const int kb = wv*256 + ks*32 + ((lane >> 4) & 3)*8;
  unsigned short o[8];
#pragma unroll
  for (int i = 0; i < 8; ++i)
    o[i] = f2bf(Weg[(size_t)(kb + i)*1024 + col]);
  bh8 v; __builtin_memcpy(&v, o, 16);
  wegfrag[((size_t)(jb*4 + wv)*16 + ks*2 + ct)*64 + lane] = v;
}

// ---------------- init: zero tag buffers + team counters; bias concat ----------------
__global__ __launch_bounds__(256) void init_k(
    u32* h_tag, u32* g_tag, int* teamcnt,
    const float* __restrict__ bi, const float* __restrict__ bfv,
    const float* __restrict__ bg, const float* __restrict__ bo,
    float* __restrict__ bcat) {
  int t = blockIdx.x * 256 + threadIdx.x;
  if (t < 8192) { h_tag[t] = 0u; g_tag[t] = 0u; }   // value bf16(0), tag 0
  if (t < 32) teamcnt[t] = 0;
  if (t < 4096) {
    float v = (t < 1024) ? bi[t] : (t < 2048) ? bfv[t-1024]
            : (t < 3072) ? bg[t-2048] : bo[t-3072];
    bcat[t] = v;
  }
}

// ---------------- convert x to bf16 ----------------
__global__ __launch_bounds__(256) void conv_x(const float* __restrict__ x,
                                              __hip_bfloat16* __restrict__ xbf) {
  size_t i = ((size_t)blockIdx.x * 256 + threadIdx.x) * 8;
  fx4 a = *reinterpret_cast<const fx4*>(x + i);
  fx4 b = *reinterpret_cast<const fx4*>(x + i + 4);
  unsigned short o[8];
#pragma unroll
  for (int u = 0; u < 4; ++u) { o[u] = f2bf(a[u]); o[4+u] = f2bf(b[u]); }
  bh8 v; __builtin_memcpy(&v, o, 16);
  *reinterpret_cast<bh8*>(xbf + i) = v;
}

// ---------------- phase-1 GEMM: XG[s*8+b][c] = x @ Wx + bias (bf16) ----------------
__global__ __launch_bounds__(256) void gemm_x(
    const __hip_bfloat16* __restrict__ xbf,
    const __hip_bfloat16* __restrict__ WxT,
    const float* __restrict__ bcat,
    __hip_bfloat16* __restrict__ XG) {
  __shared__ bh8 ldsv[2048];                 // 32 KB
  char* lds = reinterpret_cast<char*>(ldsv);
  const int tid = threadIdx.x;
  const int bn = blockIdx.x, bm = blockIdx.y;
  const int lane = tid & 63, wid = tid >> 6;
  const int wr = wid >> 1, wc = wid & 1;
  fx4 acc[4][4] = {};
  for (int kb = 0; kb < 16; ++kb) {
    __syncthreads();
#pragma unroll
    for (int c = 0; c < 4; ++c) {
      int cid = tid + 256 * c;
      int r = cid >> 3, kc = cid & 7;
      bh8 va = *reinterpret_cast<const bh8*>(xbf + (size_t)(bm*128 + r)*1024 + kb*64 + kc*8);
      int off = (r*128 + kc*16) ^ ((r & 7) << 4);
      *reinterpret_cast<bh8*>(lds + off) = va;
      bh8 vb = *reinterpret_cast<const bh8*>(WxT + (size_t)(bn*128 + r)*1024 + kb*64 + kc*8);
      *reinterpret_cast<bh8*>(lds + 16384 + off) = vb;
    }
    __syncthreads();
#pragma unroll
    for (int ks = 0; ks < 2; ++ks) {
      bh8 af[4], bfr[4];
      int ac = ks*64 + (lane >> 4) * 16;
#pragma unroll
      for (int i = 0; i < 4; ++i) {
        int ar = wr*64 + i*16 + (lane & 15);
        af[i] = *reinterpret_cast<const bh8*>(lds + ((ar*128 + ac) ^ ((ar & 7) << 4)));
        int br = wc*64 + i*16 + (lane & 15);
        bfr[i] = *reinterpret_cast<const bh8*>(lds + 16384 + ((br*128 + ac) ^ ((br & 7) << 4)));
      }
#pragma unroll
      for (int i = 0; i < 4; ++i)
#pragma unroll
        for (int jn = 0; jn < 4; ++jn)
          acc[i][jn] = __builtin_amdgcn_mfma_f32_16x16x32_bf16(af[i], bfr[jn], acc[i][jn], 0, 0, 0);
    }
  }
#pragma unroll
  for (int i = 0; i < 4; ++i) {
    int rbase = bm*128 + wr*64 + i*16 + (lane >> 4) * 4;
#pragma unroll
    for (int jn = 0; jn < 4; ++jn) {
      int col = bn*128 + wc*64 + jn*16 + (lane & 15);
      float bias = bcat[col];
#pragma unroll
      for (int jj = 0; jj < 4; ++jj) {
        int r = rbase + jj;
        int b = r >> 11, s = r & 2047;
        XG[(size_t)(s*8 + b)*4096 + col] = __float2bfloat16(acc[i][jn][jj] + bias);
      }
    }
  }
}

// ---------------- XCD-local loads: sc0 = bypass L1, hit local L2 ----------------
__device__ __forceinline__ ux4 ld_sc0(const u32* p) {
  ux4 r;
  asm volatile("global_load_dwordx4 %0, %1, off sc0\n\ts_waitcnt vmcnt(0)"
               : "=v"(r) : "v"(p) : "memory");
  return r;
}
__device__ __forceinline__ ux4 ld_sc01(const u32* p) {   // L3 fallback (safety)
  ux4 r;
  asm volatile("global_load_dwordx4 %0, %1, off sc0 sc1\n\ts_waitcnt vmcnt(0)"
               : "=v"(r) : "v"(p) : "memory");
  return r;
}

// ---------------- persistent recurrence: batch-per-XCD, L2-local tagged exchange ----
__global__ __launch_bounds__(256, 1) void recur(
    const bh8* __restrict__ gfrag, const bh8* __restrict__ wegfrag,
    const __hip_bfloat16* __restrict__ XG, const float* __restrict__ beg,
    u32* h_tag, u32* g_tag, int* teamcnt, float* d_out) {
  __shared__ bh8 wlds[3584];                 // 56 KB: gate B-frags, ks 0..6
  __shared__ unsigned short hstage[1024];    // 2 KB
  __shared__ unsigned short gstage[1024];    // 2 KB
  __shared__ float act_lds[128];
  __shared__ float exk[128];
  __shared__ unsigned short xg_lds[2][128];
  __shared__ int sh_xid, sh_jb;

  const int tid = threadIdx.x;
  const int w = tid >> 6, lane = tid & 63, rgrp = lane >> 4;

  // rendezvous: team = physical XCD, role jb = claim order within team
  if (tid == 0) {
    u32 xid;
    asm volatile("s_getreg_b32 %0, hwreg(HW_REG_XCC_ID)" : "=s"(xid));
    xid &= 7u;
    sh_xid = (int)xid;
    sh_jb = atomicAdd(&teamcnt[xid], 1) & 31;
  }
  __syncthreads();
  const int b = sh_xid, jb = sh_jb;          // batch b, owns h-cols [jb*32, jb*32+32)

  // stage LDS gate-weight fragments (ks 0..6)
  for (int r = 0; r < 14; ++r) {
    int i = r*256 + tid;
    int g = i / 896, rem = i % 896;          // rem = (2ks+ct)*64 + lane
    wlds[g*896 + rem] = gfrag[((size_t)(jb*4 + g)*64 + (rem >> 6))*64 + (rem & 63)];
  }
  // VGPR gate-weight fragments (ks 7..31) — statically indexed
  bh8 wreg[50];
#pragma unroll
  for (int q = 0; q < 50; ++q) {
    int ks = 7 + (q >> 1), ct = q & 1;
    wreg[q] = gfrag[((size_t)(jb*4 + w)*64 + ks*2 + ct)*64 + lane];
  }
  bh8 wegreg[16];
#pragma unroll
  for (int q = 0; q < 16; ++q)
    wegreg[q] = wegfrag[((size_t)(jb*4 + w)*16 + q)*64 + lane];

  float begv = 0.f, c_st = 0.f, n_st = 0.f;
  float i_v = 0.f, f_v = 0.f, o_v = 0.f, c_new = 0.f;
  if (tid < 32) begv = beg[jb*32 + tid];
  if (tid < 32) {  // stage XG[0]
    int gate = tid >> 3, ch = tid & 7;
    u64 v = *reinterpret_cast<const u64*>(
        &XG[((size_t)b)*4096 + gate*1024 + jb*32 + ch*4]);
    reinterpret_cast<u64*>(&xg_lds[0][0])[tid] = v;
  }
  __syncthreads();

#pragma unroll 1
  for (int t = 0; t < S_LEN; ++t) {
    // issue next-step XG loads early (hidden under poll)
    u64 xgv = 0;
    const int q32 = tid - 192;
    if (q32 >= 0 && q32 < 32 && t < S_LEN - 1) {
      int gate = q32 >> 3, ch = q32 & 7;
      xgv = *reinterpret_cast<const u64*>(
          &XG[((size_t)(t+1)*8 + b)*4096 + gate*1024 + jb*32 + ch*4]);
    }
    // ---- poll h (tag t), stage to LDS ----
    {
      const u32* hp = h_tag + b*1024 + tid*4;
      u32 et = (u32)t; ux4 v; int rnd = 0;
      while (true) {
        v = ((++rnd) & 3) ? ld_sc0(hp) : ld_sc01(hp);
        if (!(((v.x ^ et) | (v.y ^ et) | (v.z ^ et) | (v.w ^ et)) & 0xffffu)) break;
      }
      u64 pk = (u64)((v.x >> 16) | (v.y & 0xffff0000u))
             | ((u64)((v.z >> 16) | (v.w & 0xffff0000u)) << 32);
      reinterpret_cast<u64*>(hstage)[tid] = pk;
    }
    __syncthreads();
    if (q32 >= 0 && q32 < 32 && t < S_LEN - 1)
      reinterpret_cast<u64*>(&xg_lds[(t+1) & 1][0])[q32] = xgv;
    // ---- phase A: wave w computes gate w, 32 cols, full K=1024 ----
    fx4 aa = {0,0,0,0}, ab = {0,0,0,0}, ba = {0,0,0,0}, bb = {0,0,0,0};
#pragma unroll
    for (int ks = 0; ks < 32; ++ks) {
      bh8 af = *reinterpret_cast<const bh8*>(
          reinterpret_cast<const char*>(hstage) + ks*64 + rgrp*16);
      bh8 b0 = (ks < 7) ? wlds[w*896 + (ks*2)*64 + lane]     : wreg[(ks-7)*2];
      bh8 b1 = (ks < 7) ? wlds[w*896 + (ks*2 + 1)*64 + lane] : wreg[(ks-7)*2 + 1];
      if (ks & 1) {
        ab = __builtin_amdgcn_mfma_f32_16x16x32_bf16(af, b0, ab, 0, 0, 0);
        bb = __builtin_amdgcn_mfma_f32_16x16x32_bf16(af, b1, bb, 0, 0, 0);
      } else {
        aa = __builtin_amdgcn_mfma_f32_16x16x32_bf16(af, b0, aa, 0, 0, 0);
        ba = __builtin_amdgcn_mfma_f32_16x16x32_bf16(af, b1, ba, 0, 0, 0);
      }
    }
    if (lane < 16) {                          // D row 0 lives in lanes 0-15, reg 0
      act_lds[w*32 + lane]      = aa[0] + ab[0];
      act_lds[w*32 + 16 + lane] = ba[0] + bb[0];
    }
    __syncthreads();
    if (tid < 32) {   // gates + c-state; publish g ASAP (write-through, L2-visible)
      int c = tid;
      const unsigned short* xga = &xg_lds[t & 1][0];
      float pg = act_lds[64 + c] + bf2f(xga[64 + c]);
      float g_v = tanhf(pg);
      __hip_atomic_store(&g_tag[b*1024 + jb*32 + c],
                         ((u32)f2bf(g_v) << 16) | (u32)(t + 1),
                         __ATOMIC_RELAXED, __HIP_MEMORY_SCOPE_AGENT);
      float pi = act_lds[c]      + bf2f(xga[c]);
      float pf = act_lds[32 + c] + bf2f(xga[32 + c]);
      float po = act_lds[96 + c] + bf2f(xga[96 + c]);
      i_v = 1.f / (1.f + expf(-pi));
      f_v = 1.f / (1.f + expf(-pf));
      o_v = 1.f / (1.f + expf(-po));
      c_new = f_v * c_st + i_v * g_v; c_st = c_new;
    }
    // ---- poll g (tag t+1), stage to LDS ----
    {
      const u32* gp = g_tag + b*1024 + tid*4;
      u32 et = (u32)(t + 1); ux4 v; int rnd = 0;
      while (true) {
        v = ((++rnd) & 3) ? ld_sc0(gp) : ld_sc01(gp);
        if (!(((v.x ^ et) | (v.y ^ et) | (v.z ^ et) | (v.w ^ et)) & 0xffffu)) break;
      }
      u64 pk = (u64)((v.x >> 16) | (v.y & 0xffff0000u))
             | ((u64)((v.z >> 16) | (v.w & 0xffff0000u)) << 32);
      reinterpret_cast<u64*>(gstage)[tid] = pk;
    }
    __syncthreads();
    // ---- phase B: e = g @ Weg, K split across 4 waves ----
    fx4 e0 = {0,0,0,0}, e1 = {0,0,0,0};
#pragma unroll
    for (int ks = 0; ks < 8; ++ks) {
      bh8 af = *reinterpret_cast<const bh8*>(
          reinterpret_cast<const char*>(gstage) + w*512 + ks*64 + rgrp*16);
      e0 = __builtin_amdgcn_mfma_f32_16x16x32_bf16(af, wegreg[ks*2],     e0, 0, 0, 0);
      e1 = __builtin_amdgcn_mfma_f32_16x16x32_bf16(af, wegreg[ks*2 + 1], e1, 0, 0, 0);
    }
    if (lane < 16) { exk[w*32 + lane] = e0[0]; exk[w*32 + 16 + lane] = e1[0]; }
    __syncthreads();
    if (tid < 32) {
      float s = exk[tid] + exk[32 + tid] + exk[64 + tid] + exk[96 + tid] + begv;
      float e = expf(s);
      float n_new = f_v * n_st + i_v * e; n_st = n_new;
      float h_new = o_v * (c_new / n_new);
      if (t < S_LEN - 1) {
        __hip_atomic_store(&h_tag[b*1024 + jb*32 + tid],
                           ((u32)f2bf(h_new) << 16) | (u32)(t + 1),
                           __ATOMIC_RELAXED, __HIP_MEMORY_SCOPE_AGENT);
      }
      d_out[((size_t)b*2048 + t)*1024 + jb*32 + tid] = h_new;   // h history (pre-LN)
      if (t == S_LEN - 1) {
        d_out[OUTBASE +         (size_t)b*1024 + jb*32 + tid] = h_new;  // h_f
        d_out[OUTBASE +  8192 + (size_t)b*1024 + jb*32 + tid] = c_new;  // c_f
        d_out[OUTBASE + 16384 + (size_t)b*1024 + jb*32 + tid] = n_new;  // n_f
      }
    }
  }
}

// ---------------- residual + LayerNorm (in-place on d_out) ----------------
__global__ __launch_bounds__(256) void ln_k(const float* __restrict__ x,
                                            const float* __restrict__ gamma,
                                            const float* __restrict__ beta,
                                            float* __restrict__ out) {
  const int r = blockIdx.x, tid = threadIdx.x;
  float* orow = out + (size_t)r * 1024;
  const float* xrow = x + (size_t)r * 1024;
  fx4 h4 = *reinterpret_cast<const fx4*>(orow + tid*4);
  fx4 x4 = *reinterpret_cast<const fx4*>(xrow + tid*4);
  fx4 y = h4 + x4;
  float s = y[0] + y[1] + y[2] + y[3];
  float s2 = y[0]*y[0] + y[1]*y[1] + y[2]*y[2] + y[3]*y[3];
#pragma unroll
  for (int m = 1; m < 64; m <<= 1) { s += __shfl_xor(s, m, 64); s2 += __shfl_xor(s2, m, 64); }
  __shared__ float ps[4], ps2[4], stats[2];
  if ((tid & 63) == 0) { ps[tid >> 6] = s; ps2[tid >> 6] = s2; }
  __syncthreads();
  if (tid == 0) {
    float t1 = ps[0] + ps[1] + ps[2] + ps[3];
    float t2 = ps2[0] + ps2[1] + ps2[2] + ps2[3];
    float mu = t1 * (1.f / 1024.f);
    float var = t2 * (1.f / 1024.f) - mu * mu;
    stats[0] = mu; stats[1] = rsqrtf(var + 1e-5f);
  }
  __syncthreads();
  float mu = stats[0], rs = stats[1];
  fx4 g4 = *reinterpret_cast<const fx4*>(gamma + tid*4);
  fx4 b4 = *reinterpret_cast<const fx4*>(beta + tid*4);
  fx4 o4;
#pragma unroll
  for (int u = 0; u < 4; ++u) o4[u] = (y[u] - mu) * rs * g4[u] + b4[u];
  *reinterpret_cast<fx4*>(orow + tid*4) = o4;
}

extern "C" void kernel_launch(void* const* d_in, const int* in_sizes, int n_in,
                              void* d_out, int out_size, void* d_ws, size_t ws_size,
                              hipStream_t stream) {
  const float* x    = (const float*)d_in[0];
  const float* Wi   = (const float*)d_in[1];
  const float* bi   = (const float*)d_in[2];
  const float* Wf   = (const float*)d_in[3];
  const float* bfv  = (const float*)d_in[4];
  const float* Wg   = (const float*)d_in[5];
  const float* bg   = (const float*)d_in[6];
  const float* Wo   = (const float*)d_in[7];
  const float* bo   = (const float*)d_in[8];
  const float* Weg  = (const float*)d_in[9];
  const float* beg  = (const float*)d_in[10];
  const float* gamma= (const float*)d_in[11];
  const float* beta = (const float*)d_in[12];
  float* out = (float*)d_out;
  char* ws = (char*)d_ws;

  __hip_bfloat16* XG   = (__hip_bfloat16*)(ws);                    // 134217728 B
  __hip_bfloat16* xbf  = (__hip_bfloat16*)(ws + 134217728ull);     //  33554432 B
  __hip_bfloat16* WxT  = (__hip_bfloat16*)(ws + 167772160ull);     //   8388608 B
  bh8* gfrag           = (bh8*)(ws + 176160768ull);                //   8388608 B
  bh8* wegfrag         = (bh8*)(ws + 184549376ull);                //   2097152 B
  float* bcat          = (float*)(ws + 186646528ull);              //     16384 B
  u32* h_tag           = (u32*)(ws + 186662912ull);                //     32768 B
  u32* g_tag           = (u32*)(ws + 186695680ull);                //     32768 B
  int* teamcnt         = (int*)(ws + 186728448ull);                //       128 B

  prep_w<<<dim3(32, 32, 4), dim3(32, 8), 0, stream>>>(Wi, Wf, Wg, Wo, WxT);
  prep_gfrag<<<dim3(4096), dim3(128), 0, stream>>>(Wi, Wf, Wg, Wo, gfrag);
  prep_wegfrag<<<dim3(1024), dim3(128), 0, stream>>>(Weg, wegfrag);
  init_k<<<dim3(64), dim3(256), 0, stream>>>(h_tag, g_tag, teamcnt, bi, bfv, bg, bo, bcat);
  conv_x<<<dim3(8192), dim3(256), 0, stream>>>(x, xbf);
  gemm_x<<<dim3(32, 128), dim3(256), 0, stream>>>(xbf, WxT, bcat, XG);
  recur<<<dim3(256), dim3(256), 0, stream>>>(gfrag, wegfrag, XG, beg, h_tag, g_tag, teamcnt, out);
  ln_k<<<dim3(16384), dim3(256), 0, stream>>>(x, gamma, beta, out);
}